// Round 18
// baseline (93.023 us; speedup 1.0000x reference)
//
#include <hip/hip_runtime.h>
#include <hip/hip_bf16.h>
#include <hip/hip_fp8.h>

// Problem constants (fixed by setup_inputs): B=4096, d=128, M=8192, C=16
#define B_ROWS 4096
#define D_K    128
#define M_ROWS 8192
#define N_TOT  12288   // B_ROWS + M_ROWS
#define NCHUNK 32      // j-chunks (grid.x of sim), 384 cols each
#define JT_PER_CHUNK 6 // 6 tiles of 64 cols: 32*6*64 = 12288 = N_TOT (coverage!)
#define JCOLS  64      // cols per tile
#define NCLS   16

typedef __attribute__((ext_vector_type(4))) int   intx4;
typedef __attribute__((ext_vector_type(8))) int   intx8;
typedef __attribute__((ext_vector_type(4))) float floatx4;

__device__ __forceinline__ float fp8_to_f32(unsigned char b) {
    __hip_fp8_e4m3 h; h.__x = b; return float(h);
}

// ---------------------------------------------------------------------------
// Kernel 1 (R17 + selfdot): normalize rows into fp8 G8 (+log2e-scaled A8 for
// in-batch rows). NEW: also store selfdot[row] = ||g8_row||^2 (fp8-quantized
// norm, one extra butterfly) for the algebraic fin. Block 0 zeros
// S/hist/out/cnt.
// ---------------------------------------------------------------------------
__global__ __launch_bounds__(256) void nrm_kernel(
    const float* __restrict__ f, const float* __restrict__ fneg,
    unsigned char* __restrict__ G8, unsigned char* __restrict__ A8,
    float* __restrict__ selfdot, float* __restrict__ S,
    int* __restrict__ hist, float* __restrict__ out, int* __restrict__ cnt)
{
    const int tid  = threadIdx.x;
    const int wave = tid >> 6;
    const int lane = tid & 63;
    const int row  = blockIdx.x * 4 + wave;           // grid exact: 3072*4
    if (blockIdx.x == 0) {
        #pragma unroll
        for (int k = 0; k < 8; ++k) S[tid + k * 256] = 0.f;
        if (tid < NCLS) hist[tid] = 0;
        if (tid == 0) out[0] = 0.f;
        if (tid < 33) cnt[tid] = 0;                    // 32 it-counters + svc
    }
    const float* src = (row < B_ROWS) ? (f + (size_t)row * D_K)
                                      : (fneg + (size_t)(row - B_ROWS) * D_K);
    float2 v = *reinterpret_cast<const float2*>(src + lane * 2);
    float ss = v.x * v.x + v.y * v.y;
    #pragma unroll
    for (int m = 1; m < 64; m <<= 1) ss += __shfl_xor(ss, m, 64);
    const float scale = 1.0f / fmaxf(sqrtf(ss), 1e-8f);   // 1/max(||x||, EPS)
    __hip_fp8_e4m3 q0(v.x * scale);
    __hip_fp8_e4m3 q1(v.y * scale);
    const unsigned short pk =
        (unsigned short)q0.__x | ((unsigned short)q1.__x << 8);
    *reinterpret_cast<unsigned short*>(G8 + (size_t)row * D_K + lane * 2) = pk;
    if (row < B_ROWS) {
        const float s2 = scale * 1.44269504f;             // * log2(e)
        __hip_fp8_e4m3 a0(v.x * s2);
        __hip_fp8_e4m3 a1(v.y * s2);
        const unsigned short pa =
            (unsigned short)a0.__x | ((unsigned short)a1.__x << 8);
        *reinterpret_cast<unsigned short*>(A8 + (size_t)row * D_K + lane * 2) = pa;
        // selfdot = ||g8||^2 of the quantized row (consistent with csum's S)
        const float d0 = fp8_to_f32((unsigned char)(pk & 0xff));
        const float d1 = fp8_to_f32((unsigned char)(pk >> 8));
        float sd = d0 * d0 + d1 * d1;
        #pragma unroll
        for (int m = 1; m < 64; m <<= 1) sd += __shfl_xor(sd, m, 64);
        if (lane == 0) selfdot[row] = sd;
    }
}

// ---------------------------------------------------------------------------
// Kernel 2: sim (R17-verbatim core) + csum svc blocks + NO-SPIN fan-in fin.
// Grid (32, 36): y<32 sim (1024 blocks), y>=32 csum svc (128 blocks).
//
// Fan-in (deadlock-impossible — nobody waits; the LAST arriver does the
// work, everyone else exits):
//  - sim block (it,jc): after part_d write: threadfence; atomicAdd(cnt[it]).
//    The 32nd arriver computes lsum = sum over its 128 rows of
//    log(rowExpSum - exp(selfdot)) -> atomicAdd(out, lsum/B).
//    (Needs ONLY part_d + selfdot — the S-dependence was removed
//    algebraically.)
//  - svc block: after csum merge: threadfence; atomicAdd(cnt[32]). The
//    128th arriver computes the class term
//    sum_c (<S_c,S_c> - T_c)/npos_c  (T_c from selfdot, npos from hist)
//    -> atomicAdd(out, -term/B).
//  Release: threadfence before arrive; acquire: threadfence after winning.
// ---------------------------------------------------------------------------
__global__ __launch_bounds__(256, 2) void sim_kernel(
    const unsigned char* __restrict__ G8, const unsigned char* __restrict__ A8,
    const int* __restrict__ labels, float* __restrict__ part_d,
    float* __restrict__ S, int* __restrict__ hist,
    const float* __restrict__ selfdot, float* __restrict__ out,
    int* __restrict__ cnt)
{
    __shared__ unsigned char Bs[2][JCOLS * D_K];   // 2 x 8KB
    __shared__ int   dofin;
    __shared__ float w4[4];

    const int tid  = threadIdx.x;
    const int wave = tid >> 6;
    const int lane = tid & 63;

    if (blockIdx.y >= 32) {        // ---- csum svc blocks + class-term fan-in ----
        const int svc    = (blockIdx.y - 32) * NCHUNK + blockIdx.x;  // 0..127
        const int stripe = svc & 31;   // 128-row stripe
        const int dc     = svc >> 5;   // 0..3 : 32-dim chunk
        float* Sp = (float*)&Bs[0][0];            // 2KB of the 16KB Bs
        int*   lh = (int*)(Sp + NCLS * 32);       // +64B
        for (int k = tid; k < NCLS * 32; k += 256) Sp[k] = 0.f;
        if (tid < NCLS) lh[tid] = 0;
        __syncthreads();

        const int j0 = stripe * 128;
        if (dc == 0 && tid < 128) atomicAdd(&lh[labels[j0 + tid]], 1);

        const int d = tid & 31;
        const int w = tid >> 5;               // 0..7 row-walkers
        for (int jj = w; jj < 128; jj += 8) {
            const int j = j0 + jj;
            const int c = labels[j];
            atomicAdd(&Sp[c * 32 + d],
                      fp8_to_f32(G8[(size_t)j * D_K + dc * 32 + d]));
        }
        __syncthreads();
        for (int k = tid; k < NCLS * 32; k += 256)
            atomicAdd(&S[(k >> 5) * D_K + dc * 32 + (k & 31)], Sp[k]);
        if (dc == 0 && tid < NCLS) atomicAdd(&hist[tid], lh[tid]);

        // ---- fan-in: 128th svc arriver computes the class term ----
        __syncthreads();
        if (tid == 0) {
            __threadfence();
            dofin = (atomicAdd(&cnt[32], 1) == 127) ? 1 : 0;
        }
        __syncthreads();
        if (dofin) {
            __threadfence();   // acquire: S/hist/selfdot complete
            // T_c = sum of selfdot by class (LDS histogramming)
            float* Tc = (float*)&Bs[1][0];
            if (tid < NCLS) Tc[tid] = 0.f;
            __syncthreads();
            for (int i = tid; i < B_ROWS; i += 256)
                atomicAdd(&Tc[labels[i]], selfdot[i]);
            __syncthreads();
            // per class: (<S_c,S_c> - T_c)/npos_c ; waves cover 4 classes each
            float csum = 0.f;
            for (int c = wave; c < NCLS; c += 4) {
                float2 sv = *reinterpret_cast<const float2*>(
                    S + c * D_K + lane * 2);
                float dsq = sv.x * sv.x + sv.y * sv.y;
                #pragma unroll
                for (int m = 1; m < 64; m <<= 1) dsq += __shfl_xor(dsq, m, 64);
                if (lane == 0) {
                    const int h = hist[c];
                    if (h > 1) csum += (dsq - Tc[c]) / (float)(h - 1);
                }
            }
            if (lane == 0) w4[wave] = csum;
            __syncthreads();
            if (tid == 0)
                atomicAdd(out, -(w4[0] + w4[1] + w4[2] + w4[3])
                                  * (1.0f / (float)B_ROWS));
        }
        return;
    }

    const int jc = blockIdx.x;            // 0..31
    const int it = blockIdx.y;            // 0..31
    const int i0 = it * 128 + wave * 32;

    const int r16 = lane & 15;
    const int grp = lane >> 4;            // 0..3

    // resident A fragments [a] from A8 (log2e-scaled): rows i0 + a*16 + r16
    const unsigned char* Abase = A8 + (size_t)(i0 + r16) * D_K + grp * 32;
    intx8 afr[2];
    #pragma unroll
    for (int a = 0; a < 2; ++a)
        afr[a] = *reinterpret_cast<const intx8*>(Abase + (size_t)a * 16 * D_K);

    float dsum[2][4];
    #pragma unroll
    for (int a = 0; a < 2; ++a)
        #pragma unroll
        for (int r = 0; r < 4; ++r) dsum[a][r] = 0.f;

    // staging: 8KB tile, 256 thr x 16B x 2 rounds; source granule
    // pre-swizzled gran = slot ^ ((row>>2)&1) (R16 conflict-free form)
    int srcoff[2];
    #pragma unroll
    for (int s = 0; s < 2; ++s) {
        const int row  = s * 32 + (tid >> 3);
        const int gran = (tid & 7) ^ ((row >> 2) & 1);
        srcoff[s] = row * D_K + gran * 16;
    }

    intx4 streg[2];
    {   // prologue: tile 0 -> buf 0
        const unsigned char* src =
            G8 + (size_t)(jc * JT_PER_CHUNK) * JCOLS * D_K;
        #pragma unroll
        for (int s = 0; s < 2; ++s)
            streg[s] = *reinterpret_cast<const intx4*>(src + srcoff[s]);
        #pragma unroll
        for (int s = 0; s < 2; ++s)
            *reinterpret_cast<intx4*>(&Bs[0][0] + s * 4096 + tid * 16) =
                streg[s];
    }

    for (int t = 0; t < JT_PER_CHUNK; ++t) {
        const int cur = t & 1;
        __syncthreads();   // buf[cur] written & visible; buf[cur^1] reads done

        if (t + 1 < JT_PER_CHUNK) {
            const unsigned char* src =
                G8 + (size_t)(jc * JT_PER_CHUNK + t + 1) * JCOLS * D_K;
            #pragma unroll
            for (int s = 0; s < 2; ++s)
                streg[s] = *reinterpret_cast<const intx4*>(src + srcoff[s]);
        }

        floatx4 acc[2][4];
        #pragma unroll
        for (int a = 0; a < 2; ++a)
            #pragma unroll
            for (int b = 0; b < 4; ++b)
                acc[a][b] = (floatx4){0.f, 0.f, 0.f, 0.f};

        const unsigned char* base = &Bs[cur][0];
        #pragma unroll
        for (int b = 0; b < 4; ++b) {
            const int jloc = b * 16 + r16;
            const int sw   = (jloc >> 2) & 1;            // row bit 2
            intx4 lo = *reinterpret_cast<const intx4*>(
                base + jloc * D_K + ((2 * grp)     ^ sw) * 16);
            intx4 hi = *reinterpret_cast<const intx4*>(
                base + jloc * D_K + ((2 * grp + 1) ^ sw) * 16);
            intx8 bfr;
            if (sw) { intx4 tmp = lo; lo = hi; hi = tmp; }
            #pragma unroll
            for (int e = 0; e < 4; ++e) { bfr[e] = lo[e]; bfr[e + 4] = hi[e]; }
            #pragma unroll
            for (int a = 0; a < 2; ++a)
                acc[a][b] = __builtin_amdgcn_mfma_scale_f32_16x16x128_f8f6f4(
                    afr[a], bfr, acc[a][b], 0, 0,
                    0, 0x7F7F7F7F, 0, 0x7F7F7F7F);   // unity scales
        }

        // branch-free epilogue: acc = log2e*sim -> exp2 (native v_exp_f32)
        #pragma unroll
        for (int a = 0; a < 2; ++a)
            #pragma unroll
            for (int r = 0; r < 4; ++r) {
                float s0 = exp2f(acc[a][0][r]) + exp2f(acc[a][1][r]);
                float s1 = exp2f(acc[a][2][r]) + exp2f(acc[a][3][r]);
                dsum[a][r] += s0 + s1;
            }

        if (t + 1 < JT_PER_CHUNK) {
            #pragma unroll
            for (int s = 0; s < 2; ++s)
                *reinterpret_cast<intx4*>(
                    &Bs[cur ^ 1][0] + s * 4096 + tid * 16) = streg[s];
        }
    }

    // 16-lane (column-group) reduce
    #pragma unroll
    for (int a = 0; a < 2; ++a)
        #pragma unroll
        for (int r = 0; r < 4; ++r) {
            #pragma unroll
            for (int m = 1; m < 16; m <<= 1)
                dsum[a][r] += __shfl_xor(dsum[a][r], m, 64);
        }
    if (r16 == 0) {
        #pragma unroll
        for (int a = 0; a < 2; ++a)
            #pragma unroll
            for (int r = 0; r < 4; ++r)
                part_d[(size_t)(i0 + a * 16 + grp * 4 + r) * NCHUNK + jc] =
                    dsum[a][r];
    }

    // ---- fan-in: 32nd arriver for this it computes its rows' log terms ----
    __syncthreads();
    if (tid == 0) {
        __threadfence();
        dofin = (atomicAdd(&cnt[it], 1) == NCHUNK - 1) ? 1 : 0;
    }
    __syncthreads();
    if (dofin) {
        __threadfence();   // acquire: all 32 part_d slices for this it visible
        float lsum = 0.f;
        for (int rr = wave; rr < 128; rr += 4) {
            const int i = it * 128 + rr;
            float pd = (lane < NCHUNK) ? part_d[(size_t)i * NCHUNK + lane] : 0.f;
            #pragma unroll
            for (int m = 1; m < 32; m <<= 1) pd += __shfl_xor(pd, m, 64);
            if (lane == 0)
                lsum += __logf(pd - __expf(selfdot[i]));
        }
        if (lane == 0) w4[wave] = lsum;
        __syncthreads();
        if (tid == 0)
            atomicAdd(out, (w4[0] + w4[1] + w4[2] + w4[3])
                              * (1.0f / (float)B_ROWS));
    }
}

// ---------------------------------------------------------------------------
extern "C" void kernel_launch(void* const* d_in, const int* in_sizes, int n_in,
                              void* d_out, int out_size, void* d_ws, size_t ws_size,
                              hipStream_t stream) {
    const float* f      = (const float*)d_in[0];
    const float* fneg   = (const float*)d_in[1];
    const int*   labels = (const int*)d_in[2];
    float*       out    = (float*)d_out;

    char* ws = (char*)d_ws;
    // Workspace layout (bytes):
    //   G8      : 12288*128  = 1,572,864
    //   A8      : 4096*128   =   524,288
    //   part_d  : 4096*32*4  =   524,288
    //   S       : 16*128*4   =     8,192
    //   hist    : 64 (pad)
    //   selfdot : 4096*4     =    16,384
    //   cnt     : 33*4 (pad 256)
    unsigned char* G8      = (unsigned char*)(ws);
    unsigned char* A8      = (unsigned char*)(ws + 1572864);
    float*         part_d  = (float*)(ws + 2097152);
    float*         S       = (float*)(ws + 2621440);
    int*           hist    = (int*)(ws + 2629632);
    float*         selfdot = (float*)(ws + 2629696);
    int*           cnt     = (int*)(ws + 2646080);

    nrm_kernel<<<N_TOT / 4, 256, 0, stream>>>(f, fneg, G8, A8, selfdot, S,
                                              hist, out, cnt);

    dim3 gridS(NCHUNK, 36);   // (32,36): 1024 sim blocks + 128 csum svc blocks
    sim_kernel<<<gridS, 256, 0, stream>>>(G8, A8, labels, part_d, S, hist,
                                          selfdot, out, cnt);
}

// Round 19
// 40.318 us; speedup vs baseline: 2.3072x; 2.3072x over previous
//
#include <hip/hip_runtime.h>
#include <hip/hip_bf16.h>
#include <hip/hip_fp8.h>

// Problem constants (fixed by setup_inputs): B=4096, d=128, M=8192, C=16
#define B_ROWS 4096
#define D_K    128
#define M_ROWS 8192
#define N_TOT  12288   // B_ROWS + M_ROWS
#define NCHUNK 64      // j-chunks (grid.x of sim), 192 cols each
#define JT_PER_CHUNK 3 // 3 tiles of 64 cols: 64*3*64 = 12288 = N_TOT (coverage!)
#define JCOLS  64      // cols per tile
#define NCLS   16

typedef __attribute__((ext_vector_type(4))) int   intx4;
typedef __attribute__((ext_vector_type(8))) int   intx8;
typedef __attribute__((ext_vector_type(4))) float floatx4;

__device__ __forceinline__ float fp8_to_f32(unsigned char b) {
    __hip_fp8_e4m3 h; h.__x = b; return float(h);
}

// ---------------------------------------------------------------------------
// Kernel 1 (R17-verbatim): normalize rows of f / f_neg into OCP fp8-e4m3
// G8[N_TOT][128]; in-batch rows additionally stored pre-scaled by log2(e)
// into A8 (sim A operand -> exp2 epilogue). One wave per row. Block 0 zeros
// S/hist/out.
// ---------------------------------------------------------------------------
__global__ __launch_bounds__(256) void nrm_kernel(
    const float* __restrict__ f, const float* __restrict__ fneg,
    unsigned char* __restrict__ G8, unsigned char* __restrict__ A8,
    float* __restrict__ S, int* __restrict__ hist, float* __restrict__ out)
{
    const int tid  = threadIdx.x;
    const int wave = tid >> 6;
    const int lane = tid & 63;
    const int row  = blockIdx.x * 4 + wave;           // grid exact: 3072*4
    if (blockIdx.x == 0) {
        #pragma unroll
        for (int k = 0; k < 8; ++k) S[tid + k * 256] = 0.f;
        if (tid < NCLS) hist[tid] = 0;
        if (tid == 0) out[0] = 0.f;
    }
    const float* src = (row < B_ROWS) ? (f + (size_t)row * D_K)
                                      : (fneg + (size_t)(row - B_ROWS) * D_K);
    float2 v = *reinterpret_cast<const float2*>(src + lane * 2);
    float ss = v.x * v.x + v.y * v.y;
    #pragma unroll
    for (int m = 1; m < 64; m <<= 1) ss += __shfl_xor(ss, m, 64);
    const float scale = 1.0f / fmaxf(sqrtf(ss), 1e-8f);   // 1/max(||x||, EPS)
    __hip_fp8_e4m3 q0(v.x * scale);
    __hip_fp8_e4m3 q1(v.y * scale);
    const unsigned short pk =
        (unsigned short)q0.__x | ((unsigned short)q1.__x << 8);
    *reinterpret_cast<unsigned short*>(G8 + (size_t)row * D_K + lane * 2) = pk;
    if (row < B_ROWS) {
        const float s2 = scale * 1.44269504f;             // * log2(e)
        __hip_fp8_e4m3 a0(v.x * s2);
        __hip_fp8_e4m3 a1(v.y * s2);
        const unsigned short pa =
            (unsigned short)a0.__x | ((unsigned short)a1.__x << 8);
        *reinterpret_cast<unsigned short*>(A8 + (size_t)row * D_K + lane * 2) = pa;
    }
}

// ---------------------------------------------------------------------------
// Kernel 2 (R17 core, 2x block count): sim + csum service blocks.
// ONLY structural change vs R17: NCHUNK 32->64, JT_PER_CHUNK 6->3.
// Grid (64, 34): y<32 sim = 2048 blocks (8/CU dispatched = exactly the
// co-residency cap -> 2x resident waves, half the per-block serial chain);
// y in {32,33} svc = 128 csum blocks (R17-verbatim port).
// R18 lesson: NO device-scope fences/fan-in — kernel boundary is cheaper.
// ---------------------------------------------------------------------------
__global__ __launch_bounds__(256, 2) void sim_kernel(
    const unsigned char* __restrict__ G8, const unsigned char* __restrict__ A8,
    const int* __restrict__ labels, float* __restrict__ part_d,
    float* __restrict__ S, int* __restrict__ hist)
{
    __shared__ unsigned char Bs[2][JCOLS * D_K];   // 2 x 8KB

    const int tid = threadIdx.x;

    if (blockIdx.y >= 32) {        // ---- csum service blocks (R17-verbatim) ----
        const int svc    = (blockIdx.y - 32) * NCHUNK + blockIdx.x;  // 0..127
        const int stripe = svc & 31;   // 128-row stripe
        const int dc     = svc >> 5;   // 0..3 : 32-dim chunk
        float* Sp = (float*)&Bs[0][0];            // 2KB of the 16KB Bs
        int*   lh = (int*)(Sp + NCLS * 32);       // +64B
        for (int k = tid; k < NCLS * 32; k += 256) Sp[k] = 0.f;
        if (tid < NCLS) lh[tid] = 0;
        __syncthreads();

        const int j0 = stripe * 128;
        if (dc == 0 && tid < 128) atomicAdd(&lh[labels[j0 + tid]], 1);

        const int d = tid & 31;
        const int w = tid >> 5;               // 0..7 row-walkers
        for (int jj = w; jj < 128; jj += 8) {
            const int j = j0 + jj;
            const int c = labels[j];
            atomicAdd(&Sp[c * 32 + d],
                      fp8_to_f32(G8[(size_t)j * D_K + dc * 32 + d]));
        }
        __syncthreads();
        for (int k = tid; k < NCLS * 32; k += 256)
            atomicAdd(&S[(k >> 5) * D_K + dc * 32 + (k & 31)], Sp[k]);
        if (dc == 0 && tid < NCLS) atomicAdd(&hist[tid], lh[tid]);
        return;
    }

    const int jc   = blockIdx.x;          // 0..63
    const int it   = blockIdx.y;          // 0..31
    const int wave = tid >> 6;            // 0..3 : i-quarter
    const int lane = tid & 63;
    const int i0   = it * 128 + wave * 32;

    const int r16 = lane & 15;
    const int grp = lane >> 4;            // 0..3

    // resident A fragments [a] from A8 (log2e-scaled): rows i0 + a*16 + r16
    const unsigned char* Abase = A8 + (size_t)(i0 + r16) * D_K + grp * 32;
    intx8 afr[2];
    #pragma unroll
    for (int a = 0; a < 2; ++a)
        afr[a] = *reinterpret_cast<const intx8*>(Abase + (size_t)a * 16 * D_K);

    float dsum[2][4];
    #pragma unroll
    for (int a = 0; a < 2; ++a)
        #pragma unroll
        for (int r = 0; r < 4; ++r) dsum[a][r] = 0.f;

    // staging: 8KB tile, 256 thr x 16B x 2 rounds. LDS linear byte
    // p = s*4096 + tid*16 -> row = s*32 + tid/8, slot = tid&7;
    // source granule pre-swizzled: gran = slot ^ ((row>>2)&1)
    int srcoff[2];
    #pragma unroll
    for (int s = 0; s < 2; ++s) {
        const int row  = s * 32 + (tid >> 3);
        const int gran = (tid & 7) ^ ((row >> 2) & 1);
        srcoff[s] = row * D_K + gran * 16;
    }

    intx4 streg[2];
    {   // prologue: tile 0 -> buf 0
        const unsigned char* src =
            G8 + (size_t)(jc * JT_PER_CHUNK) * JCOLS * D_K;
        #pragma unroll
        for (int s = 0; s < 2; ++s)
            streg[s] = *reinterpret_cast<const intx4*>(src + srcoff[s]);
        #pragma unroll
        for (int s = 0; s < 2; ++s)
            *reinterpret_cast<intx4*>(&Bs[0][0] + s * 4096 + tid * 16) =
                streg[s];
    }

    for (int t = 0; t < JT_PER_CHUNK; ++t) {
        const int cur = t & 1;
        __syncthreads();   // buf[cur] written & visible; buf[cur^1] reads done

        if (t + 1 < JT_PER_CHUNK) {
            const unsigned char* src =
                G8 + (size_t)(jc * JT_PER_CHUNK + t + 1) * JCOLS * D_K;
            #pragma unroll
            for (int s = 0; s < 2; ++s)
                streg[s] = *reinterpret_cast<const intx4*>(src + srcoff[s]);
        }

        floatx4 acc[2][4];
        #pragma unroll
        for (int a = 0; a < 2; ++a)
            #pragma unroll
            for (int b = 0; b < 4; ++b)
                acc[a][b] = (floatx4){0.f, 0.f, 0.f, 0.f};

        const unsigned char* base = &Bs[cur][0];
        #pragma unroll
        for (int b = 0; b < 4; ++b) {
            const int jloc = b * 16 + r16;
            const int sw   = (jloc >> 2) & 1;            // row bit 2
            intx4 lo = *reinterpret_cast<const intx4*>(
                base + jloc * D_K + ((2 * grp)     ^ sw) * 16);
            intx4 hi = *reinterpret_cast<const intx4*>(
                base + jloc * D_K + ((2 * grp + 1) ^ sw) * 16);
            intx8 bfr;
            // sw only flips granule bit0: lo/hi swap when sw==1.
            if (sw) { intx4 tmp = lo; lo = hi; hi = tmp; }
            #pragma unroll
            for (int e = 0; e < 4; ++e) { bfr[e] = lo[e]; bfr[e + 4] = hi[e]; }
            #pragma unroll
            for (int a = 0; a < 2; ++a)
                acc[a][b] = __builtin_amdgcn_mfma_scale_f32_16x16x128_f8f6f4(
                    afr[a], bfr, acc[a][b], 0, 0,
                    0, 0x7F7F7F7F, 0, 0x7F7F7F7F);   // unity scales
        }

        // branch-free epilogue: acc = log2e*sim -> exp2 (native v_exp_f32)
        #pragma unroll
        for (int a = 0; a < 2; ++a)
            #pragma unroll
            for (int r = 0; r < 4; ++r) {
                float s0 = exp2f(acc[a][0][r]) + exp2f(acc[a][1][r]);
                float s1 = exp2f(acc[a][2][r]) + exp2f(acc[a][3][r]);
                dsum[a][r] += s0 + s1;
            }

        if (t + 1 < JT_PER_CHUNK) {
            #pragma unroll
            for (int s = 0; s < 2; ++s)
                *reinterpret_cast<intx4*>(
                    &Bs[cur ^ 1][0] + s * 4096 + tid * 16) = streg[s];
        }
    }

    // 16-lane (column-group) reduce
    #pragma unroll
    for (int a = 0; a < 2; ++a)
        #pragma unroll
        for (int r = 0; r < 4; ++r) {
            #pragma unroll
            for (int m = 1; m < 16; m <<= 1)
                dsum[a][r] += __shfl_xor(dsum[a][r], m, 64);
        }
    if (r16 == 0) {
        #pragma unroll
        for (int a = 0; a < 2; ++a)
            #pragma unroll
            for (int r = 0; r < 4; ++r)
                part_d[(size_t)(i0 + a * 16 + grp * 4 + r) * NCHUNK + jc] =
                    dsum[a][r];
    }
}

// ---------------------------------------------------------------------------
// Kernel 3 (R17 + 64-slice reduce): finalize. 128 blocks x 4 waves; each
// wave owns 8 rows. Per row: denom = sum(64 partials) - exp(selfdot);
// psum = <g_i, S[lab]> - selfdot; loss = log(denom) - psum/npos.
// Block reduce -> atomicAdd(out, mean part).
// ---------------------------------------------------------------------------
__global__ __launch_bounds__(256) void fin_kernel(
    const unsigned char* __restrict__ G8, const float* __restrict__ part_d,
    const float* __restrict__ S, const int* __restrict__ labels,
    const int* __restrict__ hist, float* __restrict__ out)
{
    const int tid  = threadIdx.x;
    const int wave = tid >> 6;
    const int lane = tid & 63;

    float lsum = 0.f;
    #pragma unroll 2
    for (int rr = 0; rr < 8; ++rr) {
        const int i   = (blockIdx.x * 4 + wave) * 8 + rr;
        const int lab = labels[i];
        float pd = part_d[(size_t)i * NCHUNK + lane];   // 64 slices: all lanes
        const unsigned char* gr = G8 + (size_t)i * D_K + lane * 2;
        const float f0 = fp8_to_f32(gr[0]);
        const float f1 = fp8_to_f32(gr[1]);
        float2 sv = *reinterpret_cast<const float2*>(S + lab * D_K + lane * 2);
        float self = f0 * f0 + f1 * f1;
        float sp   = f0 * sv.x + f1 * sv.y;
        #pragma unroll
        for (int m = 1; m < 64; m <<= 1) {
            pd   += __shfl_xor(pd, m, 64);
            self += __shfl_xor(self, m, 64);
            sp   += __shfl_xor(sp, m, 64);
        }
        if (lane == 0) {
            const float npos  = (float)(hist[lab] - 1);
            const float denom = pd - __expf(self);
            lsum += __logf(denom) - (sp - self) / npos;
        }
    }
    __shared__ float w4[4];
    if (lane == 0) w4[wave] = lsum;
    __syncthreads();
    if (tid == 0)
        atomicAdd(out, (w4[0] + w4[1] + w4[2] + w4[3]) * (1.0f / (float)B_ROWS));
}

// ---------------------------------------------------------------------------
extern "C" void kernel_launch(void* const* d_in, const int* in_sizes, int n_in,
                              void* d_out, int out_size, void* d_ws, size_t ws_size,
                              hipStream_t stream) {
    const float* f      = (const float*)d_in[0];
    const float* fneg   = (const float*)d_in[1];
    const int*   labels = (const int*)d_in[2];
    float*       out    = (float*)d_out;

    char* ws = (char*)d_ws;
    // Workspace layout (bytes):
    //   G8     : 12288*128   = 1,572,864
    //   A8     : 4096*128    =   524,288
    //   part_d : 4096*64*4   = 1,048,576
    //   S      : 16*128*4    =     8,192
    //   hist   : 16*4
    unsigned char* G8     = (unsigned char*)(ws);
    unsigned char* A8     = (unsigned char*)(ws + 1572864);
    float*         part_d = (float*)(ws + 1572864 + 524288);
    float*         S      = (float*)(ws + 1572864 + 524288 + 1048576);
    int*           hist   = (int*)(ws + 1572864 + 524288 + 1048576 + 8192);

    nrm_kernel<<<N_TOT / 4, 256, 0, stream>>>(f, fneg, G8, A8, S, hist, out);

    dim3 gridS(NCHUNK, 34);   // (64,34): 2048 sim blocks + 128 csum svc blocks
    sim_kernel<<<gridS, 256, 0, stream>>>(G8, A8, labels, part_d, S, hist);

    fin_kernel<<<128, 256, 0, stream>>>(G8, part_d, S, labels, hist, out);
}

// Round 20
// 38.165 us; speedup vs baseline: 2.4374x; 1.0564x over previous
//
#include <hip/hip_runtime.h>
#include <hip/hip_bf16.h>
#include <hip/hip_fp8.h>

// Problem constants (fixed by setup_inputs): B=4096, d=128, M=8192, C=16
#define B_ROWS 4096
#define D_K    128
#define M_ROWS 8192
#define N_TOT  12288   // B_ROWS + M_ROWS
#define NCHUNK 32      // j-chunks (grid.x of sim)
#define JT_PER_CHUNK 3 // 3 tiles of 128 cols: 32*3*128 = 12288 = N_TOT (coverage!)
#define JCOLS  128     // cols per tile
#define NCLS   16

typedef __attribute__((ext_vector_type(4))) int   intx4;
typedef __attribute__((ext_vector_type(8))) int   intx8;
typedef __attribute__((ext_vector_type(4))) float floatx4;

__device__ __forceinline__ float fp8_to_f32(unsigned char b) {
    __hip_fp8_e4m3 h; h.__x = b; return float(h);
}

__device__ __forceinline__ void load_lds16(const unsigned char* g, unsigned char* l) {
    __builtin_amdgcn_global_load_lds(
        (const __attribute__((address_space(1))) void*)g,
        (__attribute__((address_space(3))) void*)l, 16, 0, 0);
}

// ---------------------------------------------------------------------------
// Kernel 1 (R17-verbatim): normalize rows of f / f_neg into OCP fp8-e4m3
// G8[N_TOT][128]; in-batch rows additionally stored pre-scaled by log2(e)
// into A8 (sim A operand -> exp2 epilogue). One wave per row. Block 0 zeros
// S/hist/out.
// ---------------------------------------------------------------------------
__global__ __launch_bounds__(256) void nrm_kernel(
    const float* __restrict__ f, const float* __restrict__ fneg,
    unsigned char* __restrict__ G8, unsigned char* __restrict__ A8,
    float* __restrict__ S, int* __restrict__ hist, float* __restrict__ out)
{
    const int tid  = threadIdx.x;
    const int wave = tid >> 6;
    const int lane = tid & 63;
    const int row  = blockIdx.x * 4 + wave;           // grid exact: 3072*4
    if (blockIdx.x == 0) {
        #pragma unroll
        for (int k = 0; k < 8; ++k) S[tid + k * 256] = 0.f;
        if (tid < NCLS) hist[tid] = 0;
        if (tid == 0) out[0] = 0.f;
    }
    const float* src = (row < B_ROWS) ? (f + (size_t)row * D_K)
                                      : (fneg + (size_t)(row - B_ROWS) * D_K);
    float2 v = *reinterpret_cast<const float2*>(src + lane * 2);
    float ss = v.x * v.x + v.y * v.y;
    #pragma unroll
    for (int m = 1; m < 64; m <<= 1) ss += __shfl_xor(ss, m, 64);
    const float scale = 1.0f / fmaxf(sqrtf(ss), 1e-8f);   // 1/max(||x||, EPS)
    __hip_fp8_e4m3 q0(v.x * scale);
    __hip_fp8_e4m3 q1(v.y * scale);
    const unsigned short pk =
        (unsigned short)q0.__x | ((unsigned short)q1.__x << 8);
    *reinterpret_cast<unsigned short*>(G8 + (size_t)row * D_K + lane * 2) = pk;
    if (row < B_ROWS) {
        const float s2 = scale * 1.44269504f;             // * log2(e)
        __hip_fp8_e4m3 a0(v.x * s2);
        __hip_fp8_e4m3 a1(v.y * s2);
        const unsigned short pa =
            (unsigned short)a0.__x | ((unsigned short)a1.__x << 8);
        *reinterpret_cast<unsigned short*>(A8 + (size_t)row * D_K + lane * 2) = pa;
    }
}

// ---------------------------------------------------------------------------
// Kernel 2 (m97-form staging): sim + csum service blocks.
// Grid (32, 36): y<32 sim (1024 blocks, 4/CU), y>=32 csum svc (128 blocks).
//
// Staging now via global_load_lds w=16 (fire-and-forget, un-sinkable, no
// VGPR receive): LINEAR LDS dest (wave-uniform base + lane*16, m104) +
// PRE-SWIZZLED per-lane global source (m173 / rule 21). Swizzle:
//   gran = slot ^ ((row>>1)&7)   (involution; both sides use it)
// ds_read distribution: lanes land exactly 8 per 16B slot = the wave64
// b128 bank floor -> 0 extra conflict cycles.
// Tiles: 3 x (128 cols x 128B) = 16KB, double-buffered (32KB LDS).
// Per tile per wave: 8 b-frags x (2 ds_read_b128 + 2 MFMA K=128 + 8 exp2).
// ---------------------------------------------------------------------------
__global__ __launch_bounds__(256, 2) void sim_kernel(
    const unsigned char* __restrict__ G8, const unsigned char* __restrict__ A8,
    const int* __restrict__ labels, float* __restrict__ part_d,
    float* __restrict__ S, int* __restrict__ hist)
{
    __shared__ unsigned char Bs[2][JCOLS * D_K];   // 2 x 16KB

    const int tid = threadIdx.x;

    if (blockIdx.y >= 32) {        // ---- csum service blocks (R17-verbatim) ----
        const int svc    = (blockIdx.y - 32) * NCHUNK + blockIdx.x;  // 0..127
        const int stripe = svc & 31;   // 128-row stripe
        const int dc     = svc >> 5;   // 0..3 : 32-dim chunk
        float* Sp = (float*)&Bs[0][0];
        int*   lh = (int*)(Sp + NCLS * 32);
        for (int k = tid; k < NCLS * 32; k += 256) Sp[k] = 0.f;
        if (tid < NCLS) lh[tid] = 0;
        __syncthreads();

        const int j0 = stripe * 128;
        if (dc == 0 && tid < 128) atomicAdd(&lh[labels[j0 + tid]], 1);

        const int d = tid & 31;
        const int w = tid >> 5;               // 0..7 row-walkers
        for (int jj = w; jj < 128; jj += 8) {
            const int j = j0 + jj;
            const int c = labels[j];
            atomicAdd(&Sp[c * 32 + d],
                      fp8_to_f32(G8[(size_t)j * D_K + dc * 32 + d]));
        }
        __syncthreads();
        for (int k = tid; k < NCLS * 32; k += 256)
            atomicAdd(&S[(k >> 5) * D_K + dc * 32 + (k & 31)], Sp[k]);
        if (dc == 0 && tid < NCLS) atomicAdd(&hist[tid], lh[tid]);
        return;
    }

    const int jc   = blockIdx.x;          // 0..31
    const int it   = blockIdx.y;          // 0..31
    const int wave = tid >> 6;            // 0..3 : i-quarter
    const int lane = tid & 63;
    const int i0   = it * 128 + wave * 32;

    const int r16 = lane & 15;
    const int grp = lane >> 4;            // 0..3

    // resident A fragments [a] from A8 (log2e-scaled): rows i0 + a*16 + r16
    const unsigned char* Abase = A8 + (size_t)(i0 + r16) * D_K + grp * 32;
    intx8 afr[2];
    #pragma unroll
    for (int a = 0; a < 2; ++a)
        afr[a] = *reinterpret_cast<const intx8*>(Abase + (size_t)a * 16 * D_K);

    float dsum[2][4];
    #pragma unroll
    for (int a = 0; a < 2; ++a)
        #pragma unroll
        for (int r = 0; r < 4; ++r) dsum[a][r] = 0.f;

    // staging source offsets: instruction (s): LDS linear byte
    // p = (s*4 + wave)*1024 + lane*16 -> row = p>>7 (128B rows),
    // slot = (p>>4)&7 = lane&7; source gran = slot ^ ((row>>1)&7).
    // Per-instruction dest base is wave-uniform; HW adds lane*16.
    int srcoff[4];
    int dstoff[4];
    #pragma unroll
    for (int s = 0; s < 4; ++s) {
        const int chunk = s * 4 + wave;            // 0..15 (1KB chunks)
        const int row   = chunk * 8 + (lane >> 3); // 0..127
        const int gran  = (lane & 7) ^ ((row >> 1) & 7);
        srcoff[s] = row * D_K + gran * 16;
        dstoff[s] = chunk * 1024;                  // wave-uniform
    }

    {   // prologue: stage tile 0 -> buf 0
        const unsigned char* src = G8 + (size_t)(jc * JT_PER_CHUNK) * JCOLS * D_K;
        #pragma unroll
        for (int s = 0; s < 4; ++s)
            load_lds16(src + srcoff[s], &Bs[0][dstoff[s]]);
    }

    for (int t = 0; t < JT_PER_CHUNK; ++t) {
        const int cur = t & 1;
        __syncthreads();   // vmcnt drained: buf[cur] staged; prev reads done

        if (t + 1 < JT_PER_CHUNK) {
            const unsigned char* src =
                G8 + (size_t)(jc * JT_PER_CHUNK + t + 1) * JCOLS * D_K;
            #pragma unroll
            for (int s = 0; s < 4; ++s)
                load_lds16(src + srcoff[s], &Bs[cur ^ 1][dstoff[s]]);
        }

        const unsigned char* base = &Bs[cur][0];
        #pragma unroll
        for (int b = 0; b < 8; ++b) {
            const int jloc = b * 16 + r16;
            const int sw   = (jloc >> 1) & 7;
            const int a0   = jloc * D_K + (((2 * grp) ^ sw) * 16);
            intx4 lo = *reinterpret_cast<const intx4*>(base + a0);
            intx4 hi = *reinterpret_cast<const intx4*>(base + (a0 ^ 16));
            if (sw & 1) { intx4 tmp = lo; lo = hi; hi = tmp; }
            intx8 bfr;
            #pragma unroll
            for (int e = 0; e < 4; ++e) { bfr[e] = lo[e]; bfr[e + 4] = hi[e]; }
            floatx4 acc[2];
            #pragma unroll
            for (int a = 0; a < 2; ++a)
                acc[a] = __builtin_amdgcn_mfma_scale_f32_16x16x128_f8f6f4(
                    afr[a], bfr, (floatx4){0.f, 0.f, 0.f, 0.f}, 0, 0,
                    0, 0x7F7F7F7F, 0, 0x7F7F7F7F);   // unity scales
            #pragma unroll
            for (int a = 0; a < 2; ++a)
                #pragma unroll
                for (int r = 0; r < 4; ++r)
                    dsum[a][r] += exp2f(acc[a][r]);
        }
    }

    // 16-lane (column-group) reduce
    #pragma unroll
    for (int a = 0; a < 2; ++a)
        #pragma unroll
        for (int r = 0; r < 4; ++r) {
            #pragma unroll
            for (int m = 1; m < 16; m <<= 1)
                dsum[a][r] += __shfl_xor(dsum[a][r], m, 64);
        }
    if (r16 == 0) {
        #pragma unroll
        for (int a = 0; a < 2; ++a)
            #pragma unroll
            for (int r = 0; r < 4; ++r)
                part_d[(size_t)(i0 + a * 16 + grp * 4 + r) * NCHUNK + jc] =
                    dsum[a][r];
    }
}

// ---------------------------------------------------------------------------
// Kernel 3 (R17-verbatim): finalize. 128 blocks x 4 waves; each wave 8 rows.
// Per row: denom = sum(32 partials) - exp(selfdot);
// psum = <g_i, S[lab]> - selfdot; loss = log(denom) - psum/npos.
// Block reduce -> atomicAdd(out, mean part).
// ---------------------------------------------------------------------------
__global__ __launch_bounds__(256) void fin_kernel(
    const unsigned char* __restrict__ G8, const float* __restrict__ part_d,
    const float* __restrict__ S, const int* __restrict__ labels,
    const int* __restrict__ hist, float* __restrict__ out)
{
    const int tid  = threadIdx.x;
    const int wave = tid >> 6;
    const int lane = tid & 63;

    float lsum = 0.f;
    #pragma unroll 2
    for (int rr = 0; rr < 8; ++rr) {
        const int i   = (blockIdx.x * 4 + wave) * 8 + rr;
        const int lab = labels[i];
        float pd = (lane < NCHUNK) ? part_d[(size_t)i * NCHUNK + lane] : 0.f;
        const unsigned char* gr = G8 + (size_t)i * D_K + lane * 2;
        const float f0 = fp8_to_f32(gr[0]);
        const float f1 = fp8_to_f32(gr[1]);
        float2 sv = *reinterpret_cast<const float2*>(S + lab * D_K + lane * 2);
        float self = f0 * f0 + f1 * f1;
        float sp   = f0 * sv.x + f1 * sv.y;
        #pragma unroll
        for (int m = 1; m < 64; m <<= 1) {
            pd   += __shfl_xor(pd, m, 64);
            self += __shfl_xor(self, m, 64);
            sp   += __shfl_xor(sp, m, 64);
        }
        if (lane == 0) {
            const float npos  = (float)(hist[lab] - 1);
            const float denom = pd - __expf(self);
            lsum += __logf(denom) - (sp - self) / npos;
        }
    }
    __shared__ float w4[4];
    if (lane == 0) w4[wave] = lsum;
    __syncthreads();
    if (tid == 0)
        atomicAdd(out, (w4[0] + w4[1] + w4[2] + w4[3]) * (1.0f / (float)B_ROWS));
}

// ---------------------------------------------------------------------------
extern "C" void kernel_launch(void* const* d_in, const int* in_sizes, int n_in,
                              void* d_out, int out_size, void* d_ws, size_t ws_size,
                              hipStream_t stream) {
    const float* f      = (const float*)d_in[0];
    const float* fneg   = (const float*)d_in[1];
    const int*   labels = (const int*)d_in[2];
    float*       out    = (float*)d_out;

    char* ws = (char*)d_ws;
    // Workspace layout (bytes):
    //   G8     : 12288*128   = 1,572,864
    //   A8     : 4096*128    =   524,288
    //   part_d : 4096*32*4   =   524,288
    //   S      : 16*128*4    =     8,192
    //   hist   : 16*4
    unsigned char* G8     = (unsigned char*)(ws);
    unsigned char* A8     = (unsigned char*)(ws + 1572864);
    float*         part_d = (float*)(ws + 1572864 + 524288);
    float*         S      = (float*)(ws + 1572864 + 524288 + 524288);
    int*           hist   = (int*)(ws + 1572864 + 524288 + 524288 + 8192);

    nrm_kernel<<<N_TOT / 4, 256, 0, stream>>>(f, fneg, G8, A8, S, hist, out);

    dim3 gridS(NCHUNK, 36);   // (32,36): 1024 sim blocks + 128 csum svc blocks
    sim_kernel<<<gridS, 256, 0, stream>>>(G8, A8, labels, part_d, S, hist);

    fin_kernel<<<128, 256, 0, stream>>>(G8, part_d, S, labels, hist, out);
}